// Round 1
// baseline (39.463 us; speedup 1.0000x reference)
//
#include <hip/hip_runtime.h>

// Problem constants (fixed by reference): B=8, N=8192, K=16, C_in=C_out=64
#define BB 8
#define NN 8192
#define KK 16
#define CC 64
#define TPB 64                     // tokens per block in K1
#define THREADS 256
#define BPB (NN / TPB)             // 128 blocks per batch
#define NBLK (BB * BPB)            // 1024 blocks
#define NTOK (BB * NN)             // 65536 tokens
#define BN_EPS 1e-5f

// K1: fused KNN-gather-mean (in x-space) + projection (aggx @ W^T) + BN partial stats.
// batch = blockIdx.x % 8 -> pins each batch's 2MB x slice to one XCD's L2.
__global__ __launch_bounds__(THREADS) void k_fused_gather(
    const float* __restrict__ x, const int* __restrict__ knn,
    const float* __restrict__ W, float* __restrict__ agg,
    float* __restrict__ partials)
{
    __shared__ float sWt[CC][CC];          // W transposed: sWt[c][o], 16KB
    __shared__ float sAgg[TPB][CC + 4];    // gathered means, padded row = 272B (16B-aligned)
    __shared__ float sRed[2][16][CC];      // stats reduction, 8KB

    const int tid   = threadIdx.x;
    const int batch = blockIdx.x & 7;
    const int chunk = blockIdx.x >> 3;
    const int n_base = chunk * TPB;

    // Load W[o][c] -> sWt[c][o] (once per block)
    for (int i = tid; i < CC * CC; i += THREADS) {
        const int o = i >> 6, c = i & 63;
        sWt[c][o] = W[i];
    }

    // ---- Phase A: gather-mean. 16 lanes per token; lane l owns channels 4l..4l+3.
    const int g = tid >> 4;    // token group 0..15
    const int l = tid & 15;    // lane in group
    const float4* __restrict__ x4 = (const float4*)x;

    for (int it = 0; it < TPB / 16; ++it) {
        const int t = it * 16 + g;
        const int n = n_base + t;
        const int idx_my = knn[(batch * NN + n) * KK + l];  // 16 consecutive ints / group
        float sx = 0.f, sy = 0.f, sz = 0.f, sw = 0.f;
        #pragma unroll
        for (int k = 0; k < KK; ++k) {
            const int idx = __shfl(idx_my, k, 16);
            const float4 v = x4[(size_t)(batch * NN + idx) * (CC / 4) + l]; // 256B/group
            sx += v.x; sy += v.y; sz += v.z; sw += v.w;
        }
        const float inv = 1.0f / KK;
        *(float4*)&sAgg[t][l * 4] = make_float4(sx * inv, sy * inv, sz * inv, sw * inv);
    }
    __syncthreads();

    // ---- Phase B: projection. Thread (tq,oq) owns tokens tq*4..+3, outputs oq*4..+3.
    const int tq = tid >> 4;
    const int oq = tid & 15;
    float acc[4][4] = {};
    #pragma unroll
    for (int c4 = 0; c4 < CC; c4 += 4) {
        float av[4][4], wv[4][4];
        #pragma unroll
        for (int t = 0; t < 4; ++t) {
            const float4 tmp = *(const float4*)&sAgg[tq * 4 + t][c4];
            av[t][0] = tmp.x; av[t][1] = tmp.y; av[t][2] = tmp.z; av[t][3] = tmp.w;
        }
        #pragma unroll
        for (int cc = 0; cc < 4; ++cc) {
            const float4 tmp = *(const float4*)&sWt[c4 + cc][oq * 4];
            wv[cc][0] = tmp.x; wv[cc][1] = tmp.y; wv[cc][2] = tmp.z; wv[cc][3] = tmp.w;
        }
        #pragma unroll
        for (int t = 0; t < 4; ++t)
            #pragma unroll
            for (int cc = 0; cc < 4; ++cc)
                #pragma unroll
                for (int o = 0; o < 4; ++o)
                    acc[t][o] += av[t][cc] * wv[cc][o];
    }

    // ---- Write agg (into d_out) + per-thread BN partials
    float4* __restrict__ agg4 = (float4*)agg;
    float ps[4] = {}, pq[4] = {};
    #pragma unroll
    for (int t = 0; t < 4; ++t) {
        const int n = n_base + tq * 4 + t;
        agg4[(size_t)(batch * NN + n) * (CC / 4) + oq] =
            make_float4(acc[t][0], acc[t][1], acc[t][2], acc[t][3]);
        #pragma unroll
        for (int o = 0; o < 4; ++o) {
            ps[o] += acc[t][o];
            pq[o] += acc[t][o] * acc[t][o];
        }
    }
    #pragma unroll
    for (int o = 0; o < 4; ++o) {
        sRed[0][tq][oq * 4 + o] = ps[o];
        sRed[1][tq][oq * 4 + o] = pq[o];
    }
    __syncthreads();
    if (tid < 128) {                 // 0..63 = sum, 64..127 = sumsq
        const int w = tid >> 6, c = tid & 63;
        float s = 0.f;
        #pragma unroll
        for (int i = 0; i < 16; ++i) s += sRed[w][i][c];
        partials[blockIdx.x * 128 + tid] = s;
    }
}

// K2: reduce 1024 partial rows -> 64 rows (deterministic, no atomics)
__global__ __launch_bounds__(128) void k_reduce1(
    const float* __restrict__ partials, float* __restrict__ p2)
{
    const int tid = threadIdx.x;
    const int j = blockIdx.x;           // 0..63
    float s = 0.f;
    #pragma unroll
    for (int i = 0; i < NBLK / 64; ++i)
        s += partials[(size_t)(j * (NBLK / 64) + i) * 128 + tid];
    p2[j * 128 + tid] = s;
}

// K3: finalize BN -> scale/shift per channel
__global__ __launch_bounds__(128) void k_stats(
    const float* __restrict__ p2, const float* __restrict__ gamma,
    const float* __restrict__ beta, float* __restrict__ ss)
{
    __shared__ float tot[128];
    const int tid = threadIdx.x;
    float s = 0.f;
    #pragma unroll
    for (int j = 0; j < 64; ++j) s += p2[j * 128 + tid];
    tot[tid] = s;
    __syncthreads();
    if (tid < CC) {
        const float invn = 1.0f / (float)NTOK;
        const float mu  = tot[tid] * invn;
        const float var = tot[64 + tid] * invn - mu * mu;
        const float sc  = gamma[tid] * rsqrtf(var + BN_EPS);
        ss[tid]      = sc;
        ss[CC + tid] = beta[tid] - mu * sc;
    }
}

// K4: in-place normalize d_out: out = agg*scale[c] + shift[c]
__global__ __launch_bounds__(256) void k_norm(
    float* __restrict__ out, const float* __restrict__ ss)
{
    const int idx = blockIdx.x * 256 + threadIdx.x;   // float4 index
    const float4 a  = ((const float4*)out)[idx];
    const int c4 = idx & (CC / 4 - 1);                // channel quad
    const float4 sc = ((const float4*)ss)[c4];
    const float4 sh = ((const float4*)ss)[CC / 4 + c4];
    ((float4*)out)[idx] = make_float4(
        fmaf(a.x, sc.x, sh.x), fmaf(a.y, sc.y, sh.y),
        fmaf(a.z, sc.z, sh.z), fmaf(a.w, sc.w, sh.w));
}

extern "C" void kernel_launch(void* const* d_in, const int* in_sizes, int n_in,
                              void* d_out, int out_size, void* d_ws, size_t ws_size,
                              hipStream_t stream)
{
    const float* x     = (const float*)d_in[0];
    const int*   knn   = (const int*)d_in[1];
    const float* W     = (const float*)d_in[2];
    const float* gamma = (const float*)d_in[3];
    const float* beta  = (const float*)d_in[4];
    float* out = (float*)d_out;

    float* partials = (float*)d_ws;            // NBLK*128 floats
    float* p2       = partials + NBLK * 128;   // 64*128 floats
    float* ss       = p2 + 64 * 128;           // 128 floats

    k_fused_gather<<<NBLK, THREADS, 0, stream>>>(x, knn, W, out, partials);
    k_reduce1<<<64, 128, 0, stream>>>(partials, p2);
    k_stats<<<1, 128, 0, stream>>>(p2, gamma, beta, ss);
    k_norm<<<out_size / 4 / 256, 256, 0, stream>>>(out, ss);
}